// Round 1
// baseline (1133.843 us; speedup 1.0000x reference)
//
#include <hip/hip_runtime.h>
#include <stdint.h>

// ---------------------------------------------------------------------------
// MoE top-2 FFN on gfx950: fp32 gating (exact expert selection), fp16 MFMA
// grouped GEMMs (m97-style: 128x128 tile, BK=64, global_load_lds width=16,
// XOR-swizzled LDS, ds_read_b128 frags).
// R3->R4: ffn2 atomic scatter-combine replaced by routed ybuf (plain fp16
// stores) + inverse-map gather combine kernel. ffn2 was latency-bound on
// 34.6M device-scope atomicAdds (MfmaUtil 12.6%). Atomic path kept as
// fallback when workspace can't hold ybuf.
// ---------------------------------------------------------------------------

typedef _Float16 f16;
typedef f16  f16x8 __attribute__((ext_vector_type(8)));
typedef f16  f16x4 __attribute__((ext_vector_type(4)));
typedef float fx4  __attribute__((ext_vector_type(4)));

#define NEXP 8
#define CHUNK 1024          // assignments per routing block
// meta layout (ints):
#define M_PART 0            // [32*8] per-block expert counts
#define M_OFF  256          // [9] expert slot offsets (padded 128)
#define M_BB   272          // [32*8] per-block scatter bases
#define M_TE   528          // [<=512] tile -> expert
#define M_TR   1040         // [<=512] tile -> first slot row

__device__ __forceinline__ void gload_lds16(const f16* g, f16* l) {
  // global->LDS DMA, 16 B/lane. LDS dest is wave-uniform base + lane*16.
  __builtin_amdgcn_global_load_lds(
      (const __attribute__((address_space(1))) void*)g,
      (__attribute__((address_space(3))) void*)l, 16, 0, 0);
}

// ---------------- w1/w3 -> interleaved fp16 slice  [E][2*FS][D] -------------
__global__ __launch_bounds__(256) void cvt_w13_kernel(const float* __restrict__ w1,
                                                      const float* __restrict__ w3,
                                                      f16* __restrict__ w13,
                                                      int D, int F, int FS, int fbase) {
  long i = (long)blockIdx.x * 256 + threadIdx.x;          // float4 id
  long n4 = (long)NEXP * 2 * FS * (D / 4);
  if (i >= n4) return;
  int d4 = (int)(i % (D / 4));
  int rr = (int)((i / (D / 4)) % (2 * FS));
  int e  = (int)(i / ((long)(D / 4) * 2 * FS));
  const float* src = ((rr & 1) ? w3 : w1) + ((long)e * F + fbase + (rr >> 1)) * D + d4 * 4;
  float4 v = *(const float4*)src;
  f16x4 o = {(f16)v.x, (f16)v.y, (f16)v.z, (f16)v.w};
  *(f16x4*)(w13 + i * 4) = o;
}

// ---------------- w2 -> fp16 k-slice  [E][D][FS] ---------------------------
__global__ __launch_bounds__(256) void cvt_w2_kernel(const float* __restrict__ w2,
                                                     f16* __restrict__ w2s,
                                                     int D, int F, int FS, int fbase) {
  long i = (long)blockIdx.x * 256 + threadIdx.x;          // float4 id
  long n4 = (long)NEXP * D * (FS / 4);
  if (i >= n4) return;
  int k4 = (int)(i % (FS / 4));
  int d  = (int)((i / (FS / 4)) % D);
  int e  = (int)(i / ((long)(FS / 4) * D));
  const float* src = w2 + ((long)e * D + d) * F + fbase + k4 * 4;
  float4 v = *(const float4*)src;
  f16x4 o = {(f16)v.x, (f16)v.y, (f16)v.z, (f16)v.w};
  *(f16x4*)(w2s + i * 4) = o;
}

// ---------------- gating: fp32 logits, top-2, x->fp16 (no atomics) ---------
__global__ __launch_bounds__(256) void gate_kernel(const float* __restrict__ x,
                                                   const float* __restrict__ gw,
                                                   f16* __restrict__ xb,
                                                   int* __restrict__ topk_id,
                                                   float* __restrict__ topk_w,
                                                   int D) {
  const int lane = threadIdx.x & 63;
  const int wave = threadIdx.x >> 6;
  const long tok = (long)blockIdx.x * 4 + wave;
  const float* xrow = x + tok * D;

  float part[NEXP];
#pragma unroll
  for (int e = 0; e < NEXP; ++e) part[e] = 0.f;

  for (int c = 0; c < D / 256; ++c) {
    int idx = (c * 64 + lane) * 4;
    float4 xv = *(const float4*)(xrow + idx);
    f16x4 o = {(f16)xv.x, (f16)xv.y, (f16)xv.z, (f16)xv.w};
    *(f16x4*)(xb + tok * D + idx) = o;
#pragma unroll
    for (int e = 0; e < NEXP; ++e) {
      float4 gv = *(const float4*)(gw + (long)e * D + idx);
      part[e] += xv.x * gv.x + xv.y * gv.y + xv.z * gv.z + xv.w * gv.w;
    }
  }
#pragma unroll
  for (int e = 0; e < NEXP; ++e)
    for (int off = 32; off; off >>= 1) part[e] += __shfl_xor(part[e], off);

  // top-2, lowest index wins ties (matches lax.top_k stable ordering)
  int i0 = 0; float m0 = part[0];
#pragma unroll
  for (int e = 1; e < NEXP; ++e) if (part[e] > m0) { m0 = part[e]; i0 = e; }
  int i1 = (i0 == 0) ? 1 : 0; float m1 = part[i1];
#pragma unroll
  for (int e = 0; e < NEXP; ++e)
    if (e != i0 && e != ((i0 == 0) ? 1 : 0) && part[e] > m1) { m1 = part[e]; i1 = e; }

  if (lane == 0) {
    // renormalized top-2 softmax == sigmoid of logit difference (fp32 exact)
    float w0 = 1.f / (1.f + expf(m1 - m0));
    float w1 = 1.f / (1.f + expf(m0 - m1));
    topk_id[2 * tok] = i0; topk_id[2 * tok + 1] = i1;
    topk_w[2 * tok] = w0;  topk_w[2 * tok + 1] = w1;
  }
}

// ---------------- per-block expert histogram (LDS, no global contention) ----
__global__ __launch_bounds__(256) void count_kernel(const int* __restrict__ topk_id,
                                                    int* __restrict__ meta, int n2) {
  __shared__ int h[NEXP];
  const int t = threadIdx.x;
  if (t < NEXP) h[t] = 0;
  __syncthreads();
  const int lo = blockIdx.x * CHUNK;
  const int hi = min(n2, lo + CHUNK);
  for (int i = lo + t; i < hi; i += 256) atomicAdd(&h[topk_id[i]], 1);
  __syncthreads();
  if (t < NEXP) meta[M_PART + blockIdx.x * NEXP + t] = h[t];
}

// ---------------- offsets + tile map + per-block bases + pad fill ----------
__global__ void setup_kernel(int* __restrict__ meta, int* __restrict__ routed_token,
                             float* __restrict__ routed_w, int MT, int CB) {
  __shared__ int s_off[NEXP], s_cnt[NEXP];
  const int t = threadIdx.x;
  if (t == 0) {
    int cnt[NEXP];
    for (int e = 0; e < NEXP; ++e) cnt[e] = 0;
    for (int b = 0; b < CB; ++b)
      for (int e = 0; e < NEXP; ++e) cnt[e] += meta[M_PART + b * NEXP + e];
    int off = 0, tt = 0;
    for (int e = 0; e < NEXP; ++e) {
      s_cnt[e] = cnt[e]; s_off[e] = off;
      meta[M_OFF + e] = off;
      int p = (cnt[e] + 127) & ~127;
      for (int i = 0; i < (p >> 7); ++i) {
        meta[M_TE + tt] = e; meta[M_TR + tt] = off + i * 128; ++tt;
      }
      off += p;
    }
    meta[M_OFF + NEXP] = off;
    for (; tt < MT; ++tt) meta[M_TE + tt] = -1;
    // exclusive per-block scatter bases
    for (int e = 0; e < NEXP; ++e) {
      int run = meta[M_OFF + e];
      for (int b = 0; b < CB; ++b) {
        meta[M_BB + b * NEXP + e] = run;
        run += meta[M_PART + b * NEXP + e];
      }
    }
  }
  __syncthreads();
  for (int e = 0; e < NEXP; ++e) {
    int start = s_off[e] + s_cnt[e];
    int end = s_off[e] + ((s_cnt[e] + 127) & ~127);
    for (int i = start + t; i < end; i += blockDim.x) {
      routed_token[i] = 0;      // pad rows -> token 0 (finite garbage)
      routed_w[i] = 0.f;        // zero gate weight kills pad contribution
    }
  }
}

// ---------------- scatter tokens into per-expert slots (LDS cursors) -------
// Also records the inverse map: assignment i -> slot position (for combine).
__global__ __launch_bounds__(256) void scatter_kernel(const int* __restrict__ topk_id,
                                                      const float* __restrict__ topk_w,
                                                      const int* __restrict__ meta,
                                                      int* __restrict__ routed_token,
                                                      float* __restrict__ routed_w,
                                                      int* __restrict__ slot_pos,
                                                      int n2) {
  __shared__ int cur[NEXP];
  const int t = threadIdx.x;
  if (t < NEXP) cur[t] = meta[M_BB + blockIdx.x * NEXP + t];
  __syncthreads();
  const int lo = blockIdx.x * CHUNK;
  const int hi = min(n2, lo + CHUNK);
  for (int i = lo + t; i < hi; i += 256) {
    int e = topk_id[i];
    int pos = atomicAdd(&cur[e], 1);
    routed_token[pos] = i >> 1;
    routed_w[pos] = topk_w[i];
    slot_pos[i] = pos;
  }
}

// ---------------- GEMM1: h = gate_w * silu(X w1^T) * (X w3^T) --------------
// Tile: 128 token-rows x 128 interleaved weight-rows (2j=w1[f0+j], 2j+1=w3).
// Waves 2x2 (64x64 each). BK=64, 2 MFMA K-steps per chunk.
__global__ __launch_bounds__(256) void ffn1_kernel(const f16* __restrict__ xb,
                                                   const f16* __restrict__ w13,
                                                   const int* __restrict__ routed_token,
                                                   const float* __restrict__ routed_w,
                                                   const int* __restrict__ meta,
                                                   f16* __restrict__ hbuf,
                                                   int D, int FS) {
  const int e = meta[M_TE + blockIdx.x];
  if (e < 0) return;
  const int r0 = meta[M_TR + blockIdx.x];
  const int f0 = blockIdx.y * 64;          // local to this F-slice

  __shared__ __align__(16) f16 smem[2 * 128 * 64];  // 32 KiB: sA | sB; epilogue reuses
  __shared__ float s_w[128];
  f16* sA = smem;
  f16* sB = smem + 128 * 64;

  const int t = threadIdx.x;
  const int lane = t & 63;
  const int wave = t >> 6;
  const int wm = (wave & 1) * 64;
  const int wn = (wave >> 1) * 64;

  if (t < 128) s_w[t] = routed_w[r0 + t];

  // staging: thread t owns granule gi=q*256+t -> row q*32+(t>>3), col-gran t&7.
  // XOR swizzle on the GLOBAL side: LDS (r,g) holds global (r, g^(r&7)).
  const int rb = t >> 3;
  const int sgg = (t & 7) ^ (rb & 7);
  const f16* aptr[4];
  const f16* bptr[4];
#pragma unroll
  for (int q = 0; q < 4; ++q) {
    int r = q * 32 + rb;
    int tok = routed_token[r0 + r];
    aptr[q] = xb + (long)tok * D + sgg * 8;
    bptr[q] = w13 + ((long)e * 2 * FS + 2 * f0 + r) * D + sgg * 8;
  }
  f16* ldsA[4]; f16* ldsB[4];
#pragma unroll
  for (int q = 0; q < 4; ++q) {
    int gbase = (q * 256 + (t & ~63)) * 8;   // wave-uniform
    ldsA[q] = sA + gbase;
    ldsB[q] = sB + gbase;
  }

  fx4 acc[4][4];
#pragma unroll
  for (int i = 0; i < 4; ++i)
#pragma unroll
    for (int j = 0; j < 4; ++j) acc[i][j] = (fx4){0.f, 0.f, 0.f, 0.f};

  for (int kc = 0; kc < D; kc += 64) {
#pragma unroll
    for (int q = 0; q < 4; ++q) {
      gload_lds16(aptr[q] + kc, ldsA[q]);
      gload_lds16(bptr[q] + kc, ldsB[q]);
    }
    __syncthreads();
#pragma unroll
    for (int ks = 0; ks < 2; ++ks) {
      f16x8 aF[4], bF[4];
      const int kg = ks * 4 + (lane >> 4);
#pragma unroll
      for (int mf = 0; mf < 4; ++mf) {
        int row = wm + mf * 16 + (lane & 15);
        aF[mf] = *(const f16x8*)(sA + row * 64 + (kg ^ (row & 7)) * 8);
      }
#pragma unroll
      for (int nf = 0; nf < 4; ++nf) {
        int row = wn + nf * 16 + (lane & 15);
        bF[nf] = *(const f16x8*)(sB + row * 64 + (kg ^ (row & 7)) * 8);
      }
#pragma unroll
      for (int mf = 0; mf < 4; ++mf)
#pragma unroll
        for (int nf = 0; nf < 4; ++nf)
          acc[mf][nf] = __builtin_amdgcn_mfma_f32_16x16x32_f16(aF[mf], bF[nf], acc[mf][nf], 0, 0, 0);
    }
    __syncthreads();
  }

  // epilogue: dedup even(w1)/odd(w3) pairing across nf-pairs so each lane
  // computes 32 UNIQUE silu values (native v_exp/v_rcp), scaled by gate w.
  f16* sH = smem;                       // [128][72] padded (+8 kills write conflicts)
  const int odd = lane & 1;
  const int j = (lane & 15) >> 1;
#pragma unroll
  for (int mf = 0; mf < 4; ++mf)
#pragma unroll
    for (int nfp = 0; nfp < 4; nfp += 2)
#pragma unroll
      for (int rg = 0; rg < 4; ++rg) {
        float v0 = acc[mf][nfp][rg];
        float v1 = acc[mf][nfp + 1][rg];
        float t0 = __shfl_xor(v0, 1);   // even lane: c3 of (nfp,   j)
        float t1 = __shfl_xor(v1, 1);   // odd  lane: c1 of (nfp+1, j)
        float c1 = odd ? t1 : v0;
        float c3 = odd ? v1 : t0;
        float ex = __expf(-c1);
        float hv = c1 * c3 * __builtin_amdgcn_rcpf(1.f + ex);
        int ml = wm + mf * 16 + (lane >> 4) * 4 + rg;
        int fl = (wn >> 1) + (nfp + odd) * 8 + j;
        sH[ml * 72 + fl] = (f16)(hv * s_w[ml]);
      }
  __syncthreads();
#pragma unroll
  for (int q = 0; q < 4; ++q) {
    int gi = q * 256 + t;
    int r = gi >> 3, gc = gi & 7;
    *(f16x8*)(hbuf + (long)(r0 + r) * FS + f0 + gc * 8) = *(const f16x8*)(sH + r * 72 + gc * 8);
  }
}

// ---------------- GEMM2: y[slot] = (h @ w2^T) slice (h pre-weighted) -------
// ybuf != nullptr: plain fp16 vector stores into routed ybuf[RMAX][D]
//                  (combined later by combine_kernel via slot_pos).
// ybuf == nullptr: legacy fp32 atomicAdd scatter into out (sliced fallback).
__global__ __launch_bounds__(256) void ffn2_kernel(const f16* __restrict__ hbuf,
                                                   const f16* __restrict__ w2s,
                                                   const int* __restrict__ routed_token,
                                                   const int* __restrict__ meta,
                                                   float* __restrict__ out,
                                                   f16* __restrict__ ybuf,
                                                   int D, int FS) {
  const int e = meta[M_TE + blockIdx.x];
  if (e < 0) return;
  const int r0 = meta[M_TR + blockIdx.x];
  const int d0 = blockIdx.y * 128;

  // 128*136 f16 = 34 KiB (>= 2*128*64 staging). Stride 136 hw = 272 B:
  // 16B-aligned for f16x8 reads, 4-row write groups land on distinct-ish banks.
  __shared__ __align__(16) f16 smem[128 * 136];
  __shared__ int s_tok[128];
  f16* sA = smem;
  f16* sB = smem + 128 * 64;

  const int t = threadIdx.x;
  const int lane = t & 63;
  const int wave = t >> 6;
  const int wm = (wave & 1) * 64;
  const int wn = (wave >> 1) * 64;

  if (t < 128) s_tok[t] = routed_token[r0 + t];

  const int rb = t >> 3;
  const int sgg = (t & 7) ^ (rb & 7);
  const f16* aptr[4];
  const f16* bptr[4];
#pragma unroll
  for (int q = 0; q < 4; ++q) {
    int r = q * 32 + rb;
    aptr[q] = hbuf + (long)(r0 + r) * FS + sgg * 8;
    bptr[q] = w2s + ((long)e * D + d0 + r) * FS + sgg * 8;
  }
  f16* ldsA[4]; f16* ldsB[4];
#pragma unroll
  for (int q = 0; q < 4; ++q) {
    int gbase = (q * 256 + (t & ~63)) * 8;
    ldsA[q] = sA + gbase;
    ldsB[q] = sB + gbase;
  }

  fx4 acc[4][4];
#pragma unroll
  for (int i = 0; i < 4; ++i)
#pragma unroll
    for (int j = 0; j < 4; ++j) acc[i][j] = (fx4){0.f, 0.f, 0.f, 0.f};

  for (int kc = 0; kc < FS; kc += 64) {
#pragma unroll
    for (int q = 0; q < 4; ++q) {
      gload_lds16(aptr[q] + kc, ldsA[q]);
      gload_lds16(bptr[q] + kc, ldsB[q]);
    }
    __syncthreads();
#pragma unroll
    for (int ks = 0; ks < 2; ++ks) {
      f16x8 aF[4], bF[4];
      const int kg = ks * 4 + (lane >> 4);
#pragma unroll
      for (int mf = 0; mf < 4; ++mf) {
        int row = wm + mf * 16 + (lane & 15);
        aF[mf] = *(const f16x8*)(sA + row * 64 + (kg ^ (row & 7)) * 8);
      }
#pragma unroll
      for (int nf = 0; nf < 4; ++nf) {
        int row = wn + nf * 16 + (lane & 15);
        bF[nf] = *(const f16x8*)(sB + row * 64 + (kg ^ (row & 7)) * 8);
      }
#pragma unroll
      for (int mf = 0; mf < 4; ++mf)
#pragma unroll
        for (int nf = 0; nf < 4; ++nf)
          acc[mf][nf] = __builtin_amdgcn_mfma_f32_16x16x32_f16(aF[mf], bF[nf], acc[mf][nf], 0, 0, 0);
    }
    __syncthreads();
  }

  if (ybuf) {
    // transpose through LDS -> coalesced f16x8 row stores (no atomics)
    f16* sH = smem;                     // [128][136]
#pragma unroll
    for (int mf = 0; mf < 4; ++mf)
#pragma unroll
      for (int nf = 0; nf < 4; ++nf)
#pragma unroll
        for (int rg = 0; rg < 4; ++rg) {
          int row = wm + mf * 16 + (lane >> 4) * 4 + rg;
          int col = wn + nf * 16 + (lane & 15);
          sH[row * 136 + col] = (f16)acc[mf][nf][rg];
        }
    __syncthreads();
#pragma unroll
    for (int q = 0; q < 8; ++q) {
      int gi = q * 256 + t;
      int r = gi >> 4, c = (gi & 15) * 8;
      *(f16x8*)(ybuf + (long)(r0 + r) * D + d0 + c) = *(const f16x8*)(sH + r * 136 + c);
    }
  } else {
    // legacy: out[tok, d0+nl] += acc  (h pre-weighted; pads add 0.0)
#pragma unroll
    for (int mf = 0; mf < 4; ++mf) {
#pragma unroll
      for (int rg = 0; rg < 4; ++rg) {
        int row = wm + mf * 16 + (lane >> 4) * 4 + rg;
        long obase = (long)s_tok[row] * D + d0;
#pragma unroll
        for (int nf = 0; nf < 4; ++nf) {
          int nl = wn + nf * 16 + (lane & 15);
          atomicAdd(out + obase + nl, acc[mf][nf][rg]);
        }
      }
    }
  }
}

// ---------------- combine: out[tok] = y[slot0] + y[slot1] ------------------
// One block per token, D/8 threads, one f16x8 granule each. Memory-bound.
__global__ __launch_bounds__(256) void combine_kernel(const f16* __restrict__ y,
                                                      const int* __restrict__ slot_pos,
                                                      float* __restrict__ out, int D) {
  const long tok = blockIdx.x;
  const int g = threadIdx.x * 8;
  const int p0 = slot_pos[2 * tok];
  const int p1 = slot_pos[2 * tok + 1];
  f16x8 a = *(const f16x8*)(y + (long)p0 * D + g);
  f16x8 b = *(const f16x8*)(y + (long)p1 * D + g);
  float* op = out + tok * D + g;
  float4 o0 = {(float)a[0] + (float)b[0], (float)a[1] + (float)b[1],
               (float)a[2] + (float)b[2], (float)a[3] + (float)b[3]};
  float4 o1 = {(float)a[4] + (float)b[4], (float)a[5] + (float)b[5],
               (float)a[6] + (float)b[6], (float)a[7] + (float)b[7]};
  *(float4*)op = o0;
  *(float4*)(op + 4) = o1;
}

// ---------------------------------------------------------------------------
extern "C" void kernel_launch(void* const* d_in, const int* in_sizes, int n_in,
                              void* d_out, int out_size, void* d_ws, size_t ws_size,
                              hipStream_t stream) {
  const float* x  = (const float*)d_in[0];
  const float* gw = (const float*)d_in[1];
  const float* w1 = (const float*)d_in[2];
  const float* w2 = (const float*)d_in[3];
  const float* w3 = (const float*)d_in[4];
  float* out = (float*)d_out;

  const int E = NEXP;
  const int D = in_sizes[1] / E;                              // 1024
  const long N = (long)in_sizes[0] / D;                       // 16384
  const int F = (int)((long)in_sizes[2] / ((long)E * D));     // 2048
  const int MT = (int)(2 * N / 128 + E);                      // 264 m-tiles max
  const long RMAX = (long)MT * 128;
  const long out_bytes = (long)out_size * 4;
  const int n2 = (int)(2 * N);
  const int CB = (n2 + CHUNK - 1) / CHUNK;                    // 32 routing blocks

  char* base = (char*)d_ws;
  long off = 0;
  int*   meta         = (int*)(base + off); off += 8 * 1024;
  int*   topk_id      = (int*)(base + off); off += 2 * N * 4;
  float* topk_w       = (float*)(base + off); off += 2 * N * 4;
  int*   slot_pos     = (int*)(base + off); off += 2 * N * 4;
  int*   routed_token = (int*)(base + off); off += RMAX * 4;
  float* routed_w     = (float*)(base + off); off += RMAX * 4;
  off = (off + 255) & ~255L;
  f16* xb = (f16*)(base + off); off += N * (long)D * 2;
  const long fixed = off;

  // choose slicing S so everything fits. Fast path: w13 lives in d_out (64MB).
  int S = 0; bool w13_in_dout = false; bool use_y = false;
  {
    long need1 = fixed + (long)E * D * F * 2 + RMAX * (long)F * 2;
    if (need1 <= (long)ws_size && out_bytes >= (long)E * 2 * F * D * 2) {
      S = 1; w13_in_dout = true;
      use_y = (need1 + RMAX * (long)D * 2) <= (long)ws_size;
    } else {
      const int cands[4] = {2, 4, 8, 16};
      for (int ci = 0; ci < 4 && !S; ++ci) {
        int s = cands[ci];
        if (F % (64 * s)) continue;
        long FSl = F / s;
        long need = fixed + (long)E * D * FSl * 2 + RMAX * FSl * 2 + (long)E * 2 * FSl * D * 2;
        if (need <= (long)ws_size) S = s;
      }
    }
  }
  if (!S) return;
  const int FS = F / S;
  f16* w2s = (f16*)(base + off); off += (long)E * D * FS * 2;
  f16* hbuf = (f16*)(base + off); off += RMAX * (long)FS * 2;
  f16* ybuf = nullptr;
  if (use_y) { ybuf = (f16*)(base + off); off += RMAX * (long)D * 2; }
  f16* w13 = w13_in_dout ? (f16*)d_out : (f16*)(base + off);

  hipMemsetAsync(meta, 0, 8 * 1024, stream);
  gate_kernel<<<(int)(N / 4), 256, 0, stream>>>(x, gw, xb, topk_id, topk_w, D);
  count_kernel<<<CB, 256, 0, stream>>>(topk_id, meta, n2);
  setup_kernel<<<1, 256, 0, stream>>>(meta, routed_token, routed_w, MT, CB);
  scatter_kernel<<<CB, 256, 0, stream>>>(topk_id, topk_w, meta, routed_token, routed_w,
                                         slot_pos, n2);

  const long n13 = (long)E * 2 * FS * (D / 4);
  const long nw2 = (long)E * D * (FS / 4);
  const int b13 = (int)((n13 + 255) / 256);
  const int bw2 = (int)((nw2 + 255) / 256);

  if (w13_in_dout) {
    cvt_w13_kernel<<<b13, 256, 0, stream>>>(w1, w3, w13, D, F, FS, 0);
    cvt_w2_kernel<<<bw2, 256, 0, stream>>>(w2, w2s, D, F, FS, 0);
    dim3 g1(MT, FS / 64);
    ffn1_kernel<<<g1, 256, 0, stream>>>(xb, w13, routed_token, routed_w, meta, hbuf, D, FS);
    dim3 g2(MT, D / 128);
    if (use_y) {
      // no memset needed: combine fully overwrites out (w13 in d_out dead now)
      ffn2_kernel<<<g2, 256, 0, stream>>>(hbuf, w2s, routed_token, meta, out, ybuf, D, FS);
      combine_kernel<<<(int)N, D / 8, 0, stream>>>(ybuf, slot_pos, out, D);
    } else {
      hipMemsetAsync(out, 0, out_bytes, stream);   // w13 (in d_out) dead now
      ffn2_kernel<<<g2, 256, 0, stream>>>(hbuf, w2s, routed_token, meta, out, nullptr, D, FS);
    }
  } else {
    hipMemsetAsync(out, 0, out_bytes, stream);
    for (int s = 0; s < S; ++s) {
      int fbase = s * FS;
      cvt_w13_kernel<<<b13, 256, 0, stream>>>(w1, w3, w13, D, F, FS, fbase);
      cvt_w2_kernel<<<bw2, 256, 0, stream>>>(w2, w2s, D, F, FS, fbase);
      dim3 g1(MT, FS / 64);
      ffn1_kernel<<<g1, 256, 0, stream>>>(xb, w13, routed_token, routed_w, meta, hbuf, D, FS);
      dim3 g2(MT, D / 128);
      ffn2_kernel<<<g2, 256, 0, stream>>>(hbuf, w2s, routed_token, meta, out, nullptr, D, FS);
    }
  }
}

// Round 2
// 936.750 us; speedup vs baseline: 1.2104x; 1.2104x over previous
//
#include <hip/hip_runtime.h>
#include <stdint.h>

// ---------------------------------------------------------------------------
// MoE top-2 FFN on gfx950: fp32 gating (exact expert selection), fp16 MFMA
// grouped GEMMs (m97-style: 128x128 tile, BK=64, global_load_lds width=16,
// XOR-swizzled LDS, ds_read_b128 frags).
// R4->R5: R4's ybuf path never ran (ws too small: +69MB ybuf on top of xb
// overflowed; counters were byte-identical to the atomic path). Fix: alias
// ybuf over xb (dead after ffn1) -> need 242MB instead of 275MB. Atomic and
// sliced fallbacks kept.
// ---------------------------------------------------------------------------

typedef _Float16 f16;
typedef f16  f16x8 __attribute__((ext_vector_type(8)));
typedef f16  f16x4 __attribute__((ext_vector_type(4)));
typedef float fx4  __attribute__((ext_vector_type(4)));

#define NEXP 8
#define CHUNK 1024          // assignments per routing block
// meta layout (ints):
#define M_PART 0            // [32*8] per-block expert counts
#define M_OFF  256          // [9] expert slot offsets (padded 128)
#define M_BB   272          // [32*8] per-block scatter bases
#define M_TE   528          // [<=512] tile -> expert
#define M_TR   1040         // [<=512] tile -> first slot row

__device__ __forceinline__ void gload_lds16(const f16* g, f16* l) {
  // global->LDS DMA, 16 B/lane. LDS dest is wave-uniform base + lane*16.
  __builtin_amdgcn_global_load_lds(
      (const __attribute__((address_space(1))) void*)g,
      (__attribute__((address_space(3))) void*)l, 16, 0, 0);
}

// ---------------- w1/w3 -> interleaved fp16 slice  [E][2*FS][D] -------------
__global__ __launch_bounds__(256) void cvt_w13_kernel(const float* __restrict__ w1,
                                                      const float* __restrict__ w3,
                                                      f16* __restrict__ w13,
                                                      int D, int F, int FS, int fbase) {
  long i = (long)blockIdx.x * 256 + threadIdx.x;          // float4 id
  long n4 = (long)NEXP * 2 * FS * (D / 4);
  if (i >= n4) return;
  int d4 = (int)(i % (D / 4));
  int rr = (int)((i / (D / 4)) % (2 * FS));
  int e  = (int)(i / ((long)(D / 4) * 2 * FS));
  const float* src = ((rr & 1) ? w3 : w1) + ((long)e * F + fbase + (rr >> 1)) * D + d4 * 4;
  float4 v = *(const float4*)src;
  f16x4 o = {(f16)v.x, (f16)v.y, (f16)v.z, (f16)v.w};
  *(f16x4*)(w13 + i * 4) = o;
}

// ---------------- w2 -> fp16 k-slice  [E][D][FS] ---------------------------
__global__ __launch_bounds__(256) void cvt_w2_kernel(const float* __restrict__ w2,
                                                     f16* __restrict__ w2s,
                                                     int D, int F, int FS, int fbase) {
  long i = (long)blockIdx.x * 256 + threadIdx.x;          // float4 id
  long n4 = (long)NEXP * D * (FS / 4);
  if (i >= n4) return;
  int k4 = (int)(i % (FS / 4));
  int d  = (int)((i / (FS / 4)) % D);
  int e  = (int)(i / ((long)(FS / 4) * D));
  const float* src = w2 + ((long)e * D + d) * F + fbase + k4 * 4;
  float4 v = *(const float4*)src;
  f16x4 o = {(f16)v.x, (f16)v.y, (f16)v.z, (f16)v.w};
  *(f16x4*)(w2s + i * 4) = o;
}

// ---------------- gating: fp32 logits, top-2, x->fp16 (no atomics) ---------
__global__ __launch_bounds__(256) void gate_kernel(const float* __restrict__ x,
                                                   const float* __restrict__ gw,
                                                   f16* __restrict__ xb,
                                                   int* __restrict__ topk_id,
                                                   float* __restrict__ topk_w,
                                                   int D) {
  const int lane = threadIdx.x & 63;
  const int wave = threadIdx.x >> 6;
  const long tok = (long)blockIdx.x * 4 + wave;
  const float* xrow = x + tok * D;

  float part[NEXP];
#pragma unroll
  for (int e = 0; e < NEXP; ++e) part[e] = 0.f;

  for (int c = 0; c < D / 256; ++c) {
    int idx = (c * 64 + lane) * 4;
    float4 xv = *(const float4*)(xrow + idx);
    f16x4 o = {(f16)xv.x, (f16)xv.y, (f16)xv.z, (f16)xv.w};
    *(f16x4*)(xb + tok * D + idx) = o;
#pragma unroll
    for (int e = 0; e < NEXP; ++e) {
      float4 gv = *(const float4*)(gw + (long)e * D + idx);
      part[e] += xv.x * gv.x + xv.y * gv.y + xv.z * gv.z + xv.w * gv.w;
    }
  }
#pragma unroll
  for (int e = 0; e < NEXP; ++e)
    for (int off = 32; off; off >>= 1) part[e] += __shfl_xor(part[e], off);

  // top-2, lowest index wins ties (matches lax.top_k stable ordering)
  int i0 = 0; float m0 = part[0];
#pragma unroll
  for (int e = 1; e < NEXP; ++e) if (part[e] > m0) { m0 = part[e]; i0 = e; }
  int i1 = (i0 == 0) ? 1 : 0; float m1 = part[i1];
#pragma unroll
  for (int e = 0; e < NEXP; ++e)
    if (e != i0 && e != ((i0 == 0) ? 1 : 0) && part[e] > m1) { m1 = part[e]; i1 = e; }

  if (lane == 0) {
    // renormalized top-2 softmax == sigmoid of logit difference (fp32 exact)
    float w0 = 1.f / (1.f + expf(m1 - m0));
    float w1 = 1.f / (1.f + expf(m0 - m1));
    topk_id[2 * tok] = i0; topk_id[2 * tok + 1] = i1;
    topk_w[2 * tok] = w0;  topk_w[2 * tok + 1] = w1;
  }
}

// ---------------- per-block expert histogram (LDS, no global contention) ----
__global__ __launch_bounds__(256) void count_kernel(const int* __restrict__ topk_id,
                                                    int* __restrict__ meta, int n2) {
  __shared__ int h[NEXP];
  const int t = threadIdx.x;
  if (t < NEXP) h[t] = 0;
  __syncthreads();
  const int lo = blockIdx.x * CHUNK;
  const int hi = min(n2, lo + CHUNK);
  for (int i = lo + t; i < hi; i += 256) atomicAdd(&h[topk_id[i]], 1);
  __syncthreads();
  if (t < NEXP) meta[M_PART + blockIdx.x * NEXP + t] = h[t];
}

// ---------------- offsets + tile map + per-block bases + pad fill ----------
__global__ void setup_kernel(int* __restrict__ meta, int* __restrict__ routed_token,
                             float* __restrict__ routed_w, int MT, int CB) {
  __shared__ int s_off[NEXP], s_cnt[NEXP];
  const int t = threadIdx.x;
  if (t == 0) {
    int cnt[NEXP];
    for (int e = 0; e < NEXP; ++e) cnt[e] = 0;
    for (int b = 0; b < CB; ++b)
      for (int e = 0; e < NEXP; ++e) cnt[e] += meta[M_PART + b * NEXP + e];
    int off = 0, tt = 0;
    for (int e = 0; e < NEXP; ++e) {
      s_cnt[e] = cnt[e]; s_off[e] = off;
      meta[M_OFF + e] = off;
      int p = (cnt[e] + 127) & ~127;
      for (int i = 0; i < (p >> 7); ++i) {
        meta[M_TE + tt] = e; meta[M_TR + tt] = off + i * 128; ++tt;
      }
      off += p;
    }
    meta[M_OFF + NEXP] = off;
    for (; tt < MT; ++tt) meta[M_TE + tt] = -1;
    // exclusive per-block scatter bases
    for (int e = 0; e < NEXP; ++e) {
      int run = meta[M_OFF + e];
      for (int b = 0; b < CB; ++b) {
        meta[M_BB + b * NEXP + e] = run;
        run += meta[M_PART + b * NEXP + e];
      }
    }
  }
  __syncthreads();
  for (int e = 0; e < NEXP; ++e) {
    int start = s_off[e] + s_cnt[e];
    int end = s_off[e] + ((s_cnt[e] + 127) & ~127);
    for (int i = start + t; i < end; i += blockDim.x) {
      routed_token[i] = 0;      // pad rows -> token 0 (finite garbage)
      routed_w[i] = 0.f;        // zero gate weight kills pad contribution
    }
  }
}

// ---------------- scatter tokens into per-expert slots (LDS cursors) -------
// Also records the inverse map: assignment i -> slot position (for combine).
__global__ __launch_bounds__(256) void scatter_kernel(const int* __restrict__ topk_id,
                                                      const float* __restrict__ topk_w,
                                                      const int* __restrict__ meta,
                                                      int* __restrict__ routed_token,
                                                      float* __restrict__ routed_w,
                                                      int* __restrict__ slot_pos,
                                                      int n2) {
  __shared__ int cur[NEXP];
  const int t = threadIdx.x;
  if (t < NEXP) cur[t] = meta[M_BB + blockIdx.x * NEXP + t];
  __syncthreads();
  const int lo = blockIdx.x * CHUNK;
  const int hi = min(n2, lo + CHUNK);
  for (int i = lo + t; i < hi; i += 256) {
    int e = topk_id[i];
    int pos = atomicAdd(&cur[e], 1);
    routed_token[pos] = i >> 1;
    routed_w[pos] = topk_w[i];
    slot_pos[i] = pos;
  }
}

// ---------------- GEMM1: h = gate_w * silu(X w1^T) * (X w3^T) --------------
// Tile: 128 token-rows x 128 interleaved weight-rows (2j=w1[f0+j], 2j+1=w3).
// Waves 2x2 (64x64 each). BK=64, 2 MFMA K-steps per chunk.
__global__ __launch_bounds__(256) void ffn1_kernel(const f16* __restrict__ xb,
                                                   const f16* __restrict__ w13,
                                                   const int* __restrict__ routed_token,
                                                   const float* __restrict__ routed_w,
                                                   const int* __restrict__ meta,
                                                   f16* __restrict__ hbuf,
                                                   int D, int FS) {
  const int e = meta[M_TE + blockIdx.x];
  if (e < 0) return;
  const int r0 = meta[M_TR + blockIdx.x];
  const int f0 = blockIdx.y * 64;          // local to this F-slice

  __shared__ __align__(16) f16 smem[2 * 128 * 64];  // 32 KiB: sA | sB; epilogue reuses
  __shared__ float s_w[128];
  f16* sA = smem;
  f16* sB = smem + 128 * 64;

  const int t = threadIdx.x;
  const int lane = t & 63;
  const int wave = t >> 6;
  const int wm = (wave & 1) * 64;
  const int wn = (wave >> 1) * 64;

  if (t < 128) s_w[t] = routed_w[r0 + t];

  // staging: thread t owns granule gi=q*256+t -> row q*32+(t>>3), col-gran t&7.
  // XOR swizzle on the GLOBAL side: LDS (r,g) holds global (r, g^(r&7)).
  const int rb = t >> 3;
  const int sgg = (t & 7) ^ (rb & 7);
  const f16* aptr[4];
  const f16* bptr[4];
#pragma unroll
  for (int q = 0; q < 4; ++q) {
    int r = q * 32 + rb;
    int tok = routed_token[r0 + r];
    aptr[q] = xb + (long)tok * D + sgg * 8;
    bptr[q] = w13 + ((long)e * 2 * FS + 2 * f0 + r) * D + sgg * 8;
  }
  f16* ldsA[4]; f16* ldsB[4];
#pragma unroll
  for (int q = 0; q < 4; ++q) {
    int gbase = (q * 256 + (t & ~63)) * 8;   // wave-uniform
    ldsA[q] = sA + gbase;
    ldsB[q] = sB + gbase;
  }

  fx4 acc[4][4];
#pragma unroll
  for (int i = 0; i < 4; ++i)
#pragma unroll
    for (int j = 0; j < 4; ++j) acc[i][j] = (fx4){0.f, 0.f, 0.f, 0.f};

  for (int kc = 0; kc < D; kc += 64) {
#pragma unroll
    for (int q = 0; q < 4; ++q) {
      gload_lds16(aptr[q] + kc, ldsA[q]);
      gload_lds16(bptr[q] + kc, ldsB[q]);
    }
    __syncthreads();
#pragma unroll
    for (int ks = 0; ks < 2; ++ks) {
      f16x8 aF[4], bF[4];
      const int kg = ks * 4 + (lane >> 4);
#pragma unroll
      for (int mf = 0; mf < 4; ++mf) {
        int row = wm + mf * 16 + (lane & 15);
        aF[mf] = *(const f16x8*)(sA + row * 64 + (kg ^ (row & 7)) * 8);
      }
#pragma unroll
      for (int nf = 0; nf < 4; ++nf) {
        int row = wn + nf * 16 + (lane & 15);
        bF[nf] = *(const f16x8*)(sB + row * 64 + (kg ^ (row & 7)) * 8);
      }
#pragma unroll
      for (int mf = 0; mf < 4; ++mf)
#pragma unroll
        for (int nf = 0; nf < 4; ++nf)
          acc[mf][nf] = __builtin_amdgcn_mfma_f32_16x16x32_f16(aF[mf], bF[nf], acc[mf][nf], 0, 0, 0);
    }
    __syncthreads();
  }

  // epilogue: dedup even(w1)/odd(w3) pairing across nf-pairs so each lane
  // computes 32 UNIQUE silu values (native v_exp/v_rcp), scaled by gate w.
  f16* sH = smem;                       // [128][72] padded (+8 kills write conflicts)
  const int odd = lane & 1;
  const int j = (lane & 15) >> 1;
#pragma unroll
  for (int mf = 0; mf < 4; ++mf)
#pragma unroll
    for (int nfp = 0; nfp < 4; nfp += 2)
#pragma unroll
      for (int rg = 0; rg < 4; ++rg) {
        float v0 = acc[mf][nfp][rg];
        float v1 = acc[mf][nfp + 1][rg];
        float t0 = __shfl_xor(v0, 1);   // even lane: c3 of (nfp,   j)
        float t1 = __shfl_xor(v1, 1);   // odd  lane: c1 of (nfp+1, j)
        float c1 = odd ? t1 : v0;
        float c3 = odd ? v1 : t0;
        float ex = __expf(-c1);
        float hv = c1 * c3 * __builtin_amdgcn_rcpf(1.f + ex);
        int ml = wm + mf * 16 + (lane >> 4) * 4 + rg;
        int fl = (wn >> 1) + (nfp + odd) * 8 + j;
        sH[ml * 72 + fl] = (f16)(hv * s_w[ml]);
      }
  __syncthreads();
#pragma unroll
  for (int q = 0; q < 4; ++q) {
    int gi = q * 256 + t;
    int r = gi >> 3, gc = gi & 7;
    *(f16x8*)(hbuf + (long)(r0 + r) * FS + f0 + gc * 8) = *(const f16x8*)(sH + r * 72 + gc * 8);
  }
}

// ---------------- GEMM2: y[slot] = (h @ w2^T) slice (h pre-weighted) -------
// ybuf != nullptr: plain fp16 vector stores into routed ybuf[RMAX][D]
//                  (combined later by combine_kernel via slot_pos).
// ybuf == nullptr: legacy fp32 atomicAdd scatter into out (sliced fallback).
__global__ __launch_bounds__(256) void ffn2_kernel(const f16* __restrict__ hbuf,
                                                   const f16* __restrict__ w2s,
                                                   const int* __restrict__ routed_token,
                                                   const int* __restrict__ meta,
                                                   float* __restrict__ out,
                                                   f16* __restrict__ ybuf,
                                                   int D, int FS) {
  const int e = meta[M_TE + blockIdx.x];
  if (e < 0) return;
  const int r0 = meta[M_TR + blockIdx.x];
  const int d0 = blockIdx.y * 128;

  // 128*136 f16 = 34 KiB (>= 2*128*64 staging). Stride 136 hw = 272 B:
  // 16B-aligned for f16x8 reads, 4-row write groups land on distinct-ish banks.
  __shared__ __align__(16) f16 smem[128 * 136];
  __shared__ int s_tok[128];
  f16* sA = smem;
  f16* sB = smem + 128 * 64;

  const int t = threadIdx.x;
  const int lane = t & 63;
  const int wave = t >> 6;
  const int wm = (wave & 1) * 64;
  const int wn = (wave >> 1) * 64;

  if (t < 128) s_tok[t] = routed_token[r0 + t];

  const int rb = t >> 3;
  const int sgg = (t & 7) ^ (rb & 7);
  const f16* aptr[4];
  const f16* bptr[4];
#pragma unroll
  for (int q = 0; q < 4; ++q) {
    int r = q * 32 + rb;
    aptr[q] = hbuf + (long)(r0 + r) * FS + sgg * 8;
    bptr[q] = w2s + ((long)e * D + d0 + r) * FS + sgg * 8;
  }
  f16* ldsA[4]; f16* ldsB[4];
#pragma unroll
  for (int q = 0; q < 4; ++q) {
    int gbase = (q * 256 + (t & ~63)) * 8;
    ldsA[q] = sA + gbase;
    ldsB[q] = sB + gbase;
  }

  fx4 acc[4][4];
#pragma unroll
  for (int i = 0; i < 4; ++i)
#pragma unroll
    for (int j = 0; j < 4; ++j) acc[i][j] = (fx4){0.f, 0.f, 0.f, 0.f};

  for (int kc = 0; kc < FS; kc += 64) {
#pragma unroll
    for (int q = 0; q < 4; ++q) {
      gload_lds16(aptr[q] + kc, ldsA[q]);
      gload_lds16(bptr[q] + kc, ldsB[q]);
    }
    __syncthreads();
#pragma unroll
    for (int ks = 0; ks < 2; ++ks) {
      f16x8 aF[4], bF[4];
      const int kg = ks * 4 + (lane >> 4);
#pragma unroll
      for (int mf = 0; mf < 4; ++mf) {
        int row = wm + mf * 16 + (lane & 15);
        aF[mf] = *(const f16x8*)(sA + row * 64 + (kg ^ (row & 7)) * 8);
      }
#pragma unroll
      for (int nf = 0; nf < 4; ++nf) {
        int row = wn + nf * 16 + (lane & 15);
        bF[nf] = *(const f16x8*)(sB + row * 64 + (kg ^ (row & 7)) * 8);
      }
#pragma unroll
      for (int mf = 0; mf < 4; ++mf)
#pragma unroll
        for (int nf = 0; nf < 4; ++nf)
          acc[mf][nf] = __builtin_amdgcn_mfma_f32_16x16x32_f16(aF[mf], bF[nf], acc[mf][nf], 0, 0, 0);
    }
    __syncthreads();
  }

  if (ybuf) {
    // transpose through LDS -> coalesced f16x8 row stores (no atomics)
    f16* sH = smem;                     // [128][136]
#pragma unroll
    for (int mf = 0; mf < 4; ++mf)
#pragma unroll
      for (int nf = 0; nf < 4; ++nf)
#pragma unroll
        for (int rg = 0; rg < 4; ++rg) {
          int row = wm + mf * 16 + (lane >> 4) * 4 + rg;
          int col = wn + nf * 16 + (lane & 15);
          sH[row * 136 + col] = (f16)acc[mf][nf][rg];
        }
    __syncthreads();
#pragma unroll
    for (int q = 0; q < 8; ++q) {
      int gi = q * 256 + t;
      int r = gi >> 4, c = (gi & 15) * 8;
      *(f16x8*)(ybuf + (long)(r0 + r) * D + d0 + c) = *(const f16x8*)(sH + r * 136 + c);
    }
  } else {
    // legacy: out[tok, d0+nl] += acc  (h pre-weighted; pads add 0.0)
#pragma unroll
    for (int mf = 0; mf < 4; ++mf) {
#pragma unroll
      for (int rg = 0; rg < 4; ++rg) {
        int row = wm + mf * 16 + (lane >> 4) * 4 + rg;
        long obase = (long)s_tok[row] * D + d0;
#pragma unroll
        for (int nf = 0; nf < 4; ++nf) {
          int nl = wn + nf * 16 + (lane & 15);
          atomicAdd(out + obase + nl, acc[mf][nf][rg]);
        }
      }
    }
  }
}

// ---------------- combine: out[tok] = y[slot0] + y[slot1] ------------------
// One block per token, D/8 threads, one f16x8 granule each. Memory-bound.
__global__ __launch_bounds__(256) void combine_kernel(const f16* __restrict__ y,
                                                      const int* __restrict__ slot_pos,
                                                      float* __restrict__ out, int D) {
  const long tok = blockIdx.x;
  const int g = threadIdx.x * 8;
  const int p0 = slot_pos[2 * tok];
  const int p1 = slot_pos[2 * tok + 1];
  f16x8 a = *(const f16x8*)(y + (long)p0 * D + g);
  f16x8 b = *(const f16x8*)(y + (long)p1 * D + g);
  float* op = out + tok * D + g;
  float4 o0 = {(float)a[0] + (float)b[0], (float)a[1] + (float)b[1],
               (float)a[2] + (float)b[2], (float)a[3] + (float)b[3]};
  float4 o1 = {(float)a[4] + (float)b[4], (float)a[5] + (float)b[5],
               (float)a[6] + (float)b[6], (float)a[7] + (float)b[7]};
  *(float4*)op = o0;
  *(float4*)(op + 4) = o1;
}

// ---------------------------------------------------------------------------
extern "C" void kernel_launch(void* const* d_in, const int* in_sizes, int n_in,
                              void* d_out, int out_size, void* d_ws, size_t ws_size,
                              hipStream_t stream) {
  const float* x  = (const float*)d_in[0];
  const float* gw = (const float*)d_in[1];
  const float* w1 = (const float*)d_in[2];
  const float* w2 = (const float*)d_in[3];
  const float* w3 = (const float*)d_in[4];
  float* out = (float*)d_out;

  const int E = NEXP;
  const int D = in_sizes[1] / E;                              // 1024
  const long N = (long)in_sizes[0] / D;                       // 16384
  const int F = (int)((long)in_sizes[2] / ((long)E * D));     // 2048
  const int MT = (int)(2 * N / 128 + E);                      // 264 m-tiles max
  const long RMAX = (long)MT * 128;
  const long out_bytes = (long)out_size * 4;
  const int n2 = (int)(2 * N);
  const int CB = (n2 + CHUNK - 1) / CHUNK;                    // 32 routing blocks

  char* base = (char*)d_ws;
  long off = 0;
  int*   meta         = (int*)(base + off); off += 8 * 1024;
  int*   topk_id      = (int*)(base + off); off += 2 * N * 4;
  float* topk_w       = (float*)(base + off); off += 2 * N * 4;
  int*   slot_pos     = (int*)(base + off); off += 2 * N * 4;
  int*   routed_token = (int*)(base + off); off += RMAX * 4;
  float* routed_w     = (float*)(base + off); off += RMAX * 4;
  off = (off + 255) & ~255L;
  const long small_end = off;

  const long w13_b = (long)E * 2 * F * D * 2;
  const long xb_b  = N * (long)D * 2;

  int S = 0; bool w13_in_dout = false; bool use_y = false;
  f16 *xb = nullptr, *w2s = nullptr, *hbuf = nullptr, *ybuf = nullptr, *w13 = nullptr;
  int FS = F;

  if (out_bytes >= w13_b) {
    const long w2s_b  = (long)E * D * F * 2;
    const long hbuf_b = RMAX * (long)F * 2;
    const long ybuf_b = RMAX * (long)D * 2;
    const long ovl_b  = (xb_b > ybuf_b) ? xb_b : ybuf_b;
    // Layout A: [small | w2s | hbuf | xb==ybuf overlay]  (xb dead after ffn1)
    if (small_end + w2s_b + hbuf_b + ovl_b <= (long)ws_size) {
      S = 1; w13_in_dout = true; use_y = true;
      long o = small_end;
      w2s  = (f16*)(base + o); o += w2s_b;
      hbuf = (f16*)(base + o); o += hbuf_b;
      xb   = (f16*)(base + o);
      ybuf = xb;                       // alias: ffn2 writes after ffn1's last xb read
      w13  = (f16*)d_out;
    } else if (small_end + xb_b + w2s_b + hbuf_b <= (long)ws_size) {
      // Layout B: previous fast path, atomic epilogue
      S = 1; w13_in_dout = true;
      long o = small_end;
      xb   = (f16*)(base + o); o += xb_b;
      w2s  = (f16*)(base + o); o += w2s_b;
      hbuf = (f16*)(base + o);
      w13  = (f16*)d_out;
    }
  }
  if (!S) {
    // sliced fallback: [small | xb | w2s(FS) | hbuf(FS) | w13(FS)]
    const int cands[4] = {2, 4, 8, 16};
    for (int ci = 0; ci < 4 && !S; ++ci) {
      int s = cands[ci];
      if (F % (64 * s)) continue;
      long FSl = F / s;
      long w2s_b  = (long)E * D * FSl * 2;
      long hbuf_b = RMAX * FSl * 2;
      long w13s_b = (long)E * 2 * FSl * D * 2;
      if (small_end + xb_b + w2s_b + hbuf_b + w13s_b <= (long)ws_size) {
        S = s; FS = (int)FSl;
        long o = small_end;
        xb   = (f16*)(base + o); o += xb_b;
        w2s  = (f16*)(base + o); o += w2s_b;
        hbuf = (f16*)(base + o); o += hbuf_b;
        w13  = (f16*)(base + o);
      }
    }
  }
  if (!S) return;

  hipMemsetAsync(meta, 0, 8 * 1024, stream);
  gate_kernel<<<(int)(N / 4), 256, 0, stream>>>(x, gw, xb, topk_id, topk_w, D);
  count_kernel<<<CB, 256, 0, stream>>>(topk_id, meta, n2);
  setup_kernel<<<1, 256, 0, stream>>>(meta, routed_token, routed_w, MT, CB);
  scatter_kernel<<<CB, 256, 0, stream>>>(topk_id, topk_w, meta, routed_token, routed_w,
                                         slot_pos, n2);

  const long n13 = (long)E * 2 * FS * (D / 4);
  const long nw2 = (long)E * D * (FS / 4);
  const int b13 = (int)((n13 + 255) / 256);
  const int bw2 = (int)((nw2 + 255) / 256);

  if (w13_in_dout) {
    cvt_w13_kernel<<<b13, 256, 0, stream>>>(w1, w3, w13, D, F, FS, 0);
    cvt_w2_kernel<<<bw2, 256, 0, stream>>>(w2, w2s, D, F, FS, 0);
    dim3 g1(MT, FS / 64);
    ffn1_kernel<<<g1, 256, 0, stream>>>(xb, w13, routed_token, routed_w, meta, hbuf, D, FS);
    dim3 g2(MT, D / 128);
    if (use_y) {
      // no out memset needed: combine fully overwrites out (w13 in d_out dead now)
      ffn2_kernel<<<g2, 256, 0, stream>>>(hbuf, w2s, routed_token, meta, out, ybuf, D, FS);
      combine_kernel<<<(int)N, D / 8, 0, stream>>>(ybuf, slot_pos, out, D);
    } else {
      hipMemsetAsync(out, 0, out_bytes, stream);   // w13 (in d_out) dead now
      ffn2_kernel<<<g2, 256, 0, stream>>>(hbuf, w2s, routed_token, meta, out, nullptr, D, FS);
    }
  } else {
    hipMemsetAsync(out, 0, out_bytes, stream);
    for (int s = 0; s < S; ++s) {
      int fbase = s * FS;
      cvt_w13_kernel<<<b13, 256, 0, stream>>>(w1, w3, w13, D, F, FS, fbase);
      cvt_w2_kernel<<<bw2, 256, 0, stream>>>(w2, w2s, D, F, FS, fbase);
      dim3 g1(MT, FS / 64);
      ffn1_kernel<<<g1, 256, 0, stream>>>(xb, w13, routed_token, routed_w, meta, hbuf, D, FS);
      dim3 g2(MT, D / 128);
      ffn2_kernel<<<g2, 256, 0, stream>>>(hbuf, w2s, routed_token, meta, out, nullptr, D, FS);
    }
  }
}

// Round 3
// 922.784 us; speedup vs baseline: 1.2287x; 1.0151x over previous
//
#include <hip/hip_runtime.h>
#include <stdint.h>

// ---------------------------------------------------------------------------
// MoE top-2 FFN on gfx950: fp32 gating (exact expert selection), fp16 MFMA
// grouped GEMMs (m97-style: 128x128 tile, BK=64, global_load_lds width=16,
// XOR-swizzled LDS, ds_read_b128 frags), routed ybuf + gather combine.
// R5->R6: grid-order locality fix. ffn1 FETCH was 1.12GB (~16x xb re-read):
// grid was (m-tile, f-slice) x-fastest, so each f-sweep re-streamed all of
// xb from HBM. Swap to (slice, m-tile): consecutive blocks share the A-tile
// (fetched once), B panels reuse in L2/L3. Same fix in ffn2 (hbuf was
// re-read 8x). ffn2 ybuf path skips dead s_tok load.
// ---------------------------------------------------------------------------

typedef _Float16 f16;
typedef f16  f16x8 __attribute__((ext_vector_type(8)));
typedef f16  f16x4 __attribute__((ext_vector_type(4)));
typedef float fx4  __attribute__((ext_vector_type(4)));

#define NEXP 8
#define CHUNK 1024          // assignments per routing block
// meta layout (ints):
#define M_PART 0            // [32*8] per-block expert counts
#define M_OFF  256          // [9] expert slot offsets (padded 128)
#define M_BB   272          // [32*8] per-block scatter bases
#define M_TE   528          // [<=512] tile -> expert
#define M_TR   1040         // [<=512] tile -> first slot row

__device__ __forceinline__ void gload_lds16(const f16* g, f16* l) {
  // global->LDS DMA, 16 B/lane. LDS dest is wave-uniform base + lane*16.
  __builtin_amdgcn_global_load_lds(
      (const __attribute__((address_space(1))) void*)g,
      (__attribute__((address_space(3))) void*)l, 16, 0, 0);
}

// ---------------- w1/w3 -> interleaved fp16 slice  [E][2*FS][D] -------------
__global__ __launch_bounds__(256) void cvt_w13_kernel(const float* __restrict__ w1,
                                                      const float* __restrict__ w3,
                                                      f16* __restrict__ w13,
                                                      int D, int F, int FS, int fbase) {
  long i = (long)blockIdx.x * 256 + threadIdx.x;          // float4 id
  long n4 = (long)NEXP * 2 * FS * (D / 4);
  if (i >= n4) return;
  int d4 = (int)(i % (D / 4));
  int rr = (int)((i / (D / 4)) % (2 * FS));
  int e  = (int)(i / ((long)(D / 4) * 2 * FS));
  const float* src = ((rr & 1) ? w3 : w1) + ((long)e * F + fbase + (rr >> 1)) * D + d4 * 4;
  float4 v = *(const float4*)src;
  f16x4 o = {(f16)v.x, (f16)v.y, (f16)v.z, (f16)v.w};
  *(f16x4*)(w13 + i * 4) = o;
}

// ---------------- w2 -> fp16 k-slice  [E][D][FS] ---------------------------
__global__ __launch_bounds__(256) void cvt_w2_kernel(const float* __restrict__ w2,
                                                     f16* __restrict__ w2s,
                                                     int D, int F, int FS, int fbase) {
  long i = (long)blockIdx.x * 256 + threadIdx.x;          // float4 id
  long n4 = (long)NEXP * D * (FS / 4);
  if (i >= n4) return;
  int k4 = (int)(i % (FS / 4));
  int d  = (int)((i / (FS / 4)) % D);
  int e  = (int)(i / ((long)(FS / 4) * D));
  const float* src = w2 + ((long)e * D + d) * F + fbase + k4 * 4;
  float4 v = *(const float4*)src;
  f16x4 o = {(f16)v.x, (f16)v.y, (f16)v.z, (f16)v.w};
  *(f16x4*)(w2s + i * 4) = o;
}

// ---------------- gating: fp32 logits, top-2, x->fp16 (no atomics) ---------
__global__ __launch_bounds__(256) void gate_kernel(const float* __restrict__ x,
                                                   const float* __restrict__ gw,
                                                   f16* __restrict__ xb,
                                                   int* __restrict__ topk_id,
                                                   float* __restrict__ topk_w,
                                                   int D) {
  const int lane = threadIdx.x & 63;
  const int wave = threadIdx.x >> 6;
  const long tok = (long)blockIdx.x * 4 + wave;
  const float* xrow = x + tok * D;

  float part[NEXP];
#pragma unroll
  for (int e = 0; e < NEXP; ++e) part[e] = 0.f;

  for (int c = 0; c < D / 256; ++c) {
    int idx = (c * 64 + lane) * 4;
    float4 xv = *(const float4*)(xrow + idx);
    f16x4 o = {(f16)xv.x, (f16)xv.y, (f16)xv.z, (f16)xv.w};
    *(f16x4*)(xb + tok * D + idx) = o;
#pragma unroll
    for (int e = 0; e < NEXP; ++e) {
      float4 gv = *(const float4*)(gw + (long)e * D + idx);
      part[e] += xv.x * gv.x + xv.y * gv.y + xv.z * gv.z + xv.w * gv.w;
    }
  }
#pragma unroll
  for (int e = 0; e < NEXP; ++e)
    for (int off = 32; off; off >>= 1) part[e] += __shfl_xor(part[e], off);

  // top-2, lowest index wins ties (matches lax.top_k stable ordering)
  int i0 = 0; float m0 = part[0];
#pragma unroll
  for (int e = 1; e < NEXP; ++e) if (part[e] > m0) { m0 = part[e]; i0 = e; }
  int i1 = (i0 == 0) ? 1 : 0; float m1 = part[i1];
#pragma unroll
  for (int e = 0; e < NEXP; ++e)
    if (e != i0 && e != ((i0 == 0) ? 1 : 0) && part[e] > m1) { m1 = part[e]; i1 = e; }

  if (lane == 0) {
    // renormalized top-2 softmax == sigmoid of logit difference (fp32 exact)
    float w0 = 1.f / (1.f + expf(m1 - m0));
    float w1 = 1.f / (1.f + expf(m0 - m1));
    topk_id[2 * tok] = i0; topk_id[2 * tok + 1] = i1;
    topk_w[2 * tok] = w0;  topk_w[2 * tok + 1] = w1;
  }
}

// ---------------- per-block expert histogram (LDS, no global contention) ----
__global__ __launch_bounds__(256) void count_kernel(const int* __restrict__ topk_id,
                                                    int* __restrict__ meta, int n2) {
  __shared__ int h[NEXP];
  const int t = threadIdx.x;
  if (t < NEXP) h[t] = 0;
  __syncthreads();
  const int lo = blockIdx.x * CHUNK;
  const int hi = min(n2, lo + CHUNK);
  for (int i = lo + t; i < hi; i += 256) atomicAdd(&h[topk_id[i]], 1);
  __syncthreads();
  if (t < NEXP) meta[M_PART + blockIdx.x * NEXP + t] = h[t];
}

// ---------------- offsets + tile map + per-block bases + pad fill ----------
__global__ void setup_kernel(int* __restrict__ meta, int* __restrict__ routed_token,
                             float* __restrict__ routed_w, int MT, int CB) {
  __shared__ int s_off[NEXP], s_cnt[NEXP];
  const int t = threadIdx.x;
  if (t == 0) {
    int cnt[NEXP];
    for (int e = 0; e < NEXP; ++e) cnt[e] = 0;
    for (int b = 0; b < CB; ++b)
      for (int e = 0; e < NEXP; ++e) cnt[e] += meta[M_PART + b * NEXP + e];
    int off = 0, tt = 0;
    for (int e = 0; e < NEXP; ++e) {
      s_cnt[e] = cnt[e]; s_off[e] = off;
      meta[M_OFF + e] = off;
      int p = (cnt[e] + 127) & ~127;
      for (int i = 0; i < (p >> 7); ++i) {
        meta[M_TE + tt] = e; meta[M_TR + tt] = off + i * 128; ++tt;
      }
      off += p;
    }
    meta[M_OFF + NEXP] = off;
    for (; tt < MT; ++tt) meta[M_TE + tt] = -1;
    // exclusive per-block scatter bases
    for (int e = 0; e < NEXP; ++e) {
      int run = meta[M_OFF + e];
      for (int b = 0; b < CB; ++b) {
        meta[M_BB + b * NEXP + e] = run;
        run += meta[M_PART + b * NEXP + e];
      }
    }
  }
  __syncthreads();
  for (int e = 0; e < NEXP; ++e) {
    int start = s_off[e] + s_cnt[e];
    int end = s_off[e] + ((s_cnt[e] + 127) & ~127);
    for (int i = start + t; i < end; i += blockDim.x) {
      routed_token[i] = 0;      // pad rows -> token 0 (finite garbage)
      routed_w[i] = 0.f;        // zero gate weight kills pad contribution
    }
  }
}

// ---------------- scatter tokens into per-expert slots (LDS cursors) -------
// Also records the inverse map: assignment i -> slot position (for combine).
__global__ __launch_bounds__(256) void scatter_kernel(const int* __restrict__ topk_id,
                                                      const float* __restrict__ topk_w,
                                                      const int* __restrict__ meta,
                                                      int* __restrict__ routed_token,
                                                      float* __restrict__ routed_w,
                                                      int* __restrict__ slot_pos,
                                                      int n2) {
  __shared__ int cur[NEXP];
  const int t = threadIdx.x;
  if (t < NEXP) cur[t] = meta[M_BB + blockIdx.x * NEXP + t];
  __syncthreads();
  const int lo = blockIdx.x * CHUNK;
  const int hi = min(n2, lo + CHUNK);
  for (int i = lo + t; i < hi; i += 256) {
    int e = topk_id[i];
    int pos = atomicAdd(&cur[e], 1);
    routed_token[pos] = i >> 1;
    routed_w[pos] = topk_w[i];
    slot_pos[i] = pos;
  }
}

// ---------------- GEMM1: h = gate_w * silu(X w1^T) * (X w3^T) --------------
// Tile: 128 token-rows x 128 interleaved weight-rows (2j=w1[f0+j], 2j+1=w3).
// Waves 2x2 (64x64 each). BK=64, 2 MFMA K-steps per chunk.
// Grid: (FS/64, MT) — x = f-slice (fastest) so consecutive blocks share the
// A-tile (xb rows fetched once from HBM, then L2-hit for all 32 slices).
__global__ __launch_bounds__(256) void ffn1_kernel(const f16* __restrict__ xb,
                                                   const f16* __restrict__ w13,
                                                   const int* __restrict__ routed_token,
                                                   const float* __restrict__ routed_w,
                                                   const int* __restrict__ meta,
                                                   f16* __restrict__ hbuf,
                                                   int D, int FS) {
  const int e = meta[M_TE + blockIdx.y];
  if (e < 0) return;
  const int r0 = meta[M_TR + blockIdx.y];
  const int f0 = blockIdx.x * 64;          // local to this F-slice

  __shared__ __align__(16) f16 smem[2 * 128 * 64];  // 32 KiB: sA | sB; epilogue reuses
  __shared__ float s_w[128];
  f16* sA = smem;
  f16* sB = smem + 128 * 64;

  const int t = threadIdx.x;
  const int lane = t & 63;
  const int wave = t >> 6;
  const int wm = (wave & 1) * 64;
  const int wn = (wave >> 1) * 64;

  if (t < 128) s_w[t] = routed_w[r0 + t];

  // staging: thread t owns granule gi=q*256+t -> row q*32+(t>>3), col-gran t&7.
  // XOR swizzle on the GLOBAL side: LDS (r,g) holds global (r, g^(r&7)).
  const int rb = t >> 3;
  const int sgg = (t & 7) ^ (rb & 7);
  const f16* aptr[4];
  const f16* bptr[4];
#pragma unroll
  for (int q = 0; q < 4; ++q) {
    int r = q * 32 + rb;
    int tok = routed_token[r0 + r];
    aptr[q] = xb + (long)tok * D + sgg * 8;
    bptr[q] = w13 + ((long)e * 2 * FS + 2 * f0 + r) * D + sgg * 8;
  }
  f16* ldsA[4]; f16* ldsB[4];
#pragma unroll
  for (int q = 0; q < 4; ++q) {
    int gbase = (q * 256 + (t & ~63)) * 8;   // wave-uniform
    ldsA[q] = sA + gbase;
    ldsB[q] = sB + gbase;
  }

  fx4 acc[4][4];
#pragma unroll
  for (int i = 0; i < 4; ++i)
#pragma unroll
    for (int j = 0; j < 4; ++j) acc[i][j] = (fx4){0.f, 0.f, 0.f, 0.f};

  for (int kc = 0; kc < D; kc += 64) {
#pragma unroll
    for (int q = 0; q < 4; ++q) {
      gload_lds16(aptr[q] + kc, ldsA[q]);
      gload_lds16(bptr[q] + kc, ldsB[q]);
    }
    __syncthreads();
#pragma unroll
    for (int ks = 0; ks < 2; ++ks) {
      f16x8 aF[4], bF[4];
      const int kg = ks * 4 + (lane >> 4);
#pragma unroll
      for (int mf = 0; mf < 4; ++mf) {
        int row = wm + mf * 16 + (lane & 15);
        aF[mf] = *(const f16x8*)(sA + row * 64 + (kg ^ (row & 7)) * 8);
      }
#pragma unroll
      for (int nf = 0; nf < 4; ++nf) {
        int row = wn + nf * 16 + (lane & 15);
        bF[nf] = *(const f16x8*)(sB + row * 64 + (kg ^ (row & 7)) * 8);
      }
#pragma unroll
      for (int mf = 0; mf < 4; ++mf)
#pragma unroll
        for (int nf = 0; nf < 4; ++nf)
          acc[mf][nf] = __builtin_amdgcn_mfma_f32_16x16x32_f16(aF[mf], bF[nf], acc[mf][nf], 0, 0, 0);
    }
    __syncthreads();
  }

  // epilogue: dedup even(w1)/odd(w3) pairing across nf-pairs so each lane
  // computes 32 UNIQUE silu values (native v_exp/v_rcp), scaled by gate w.
  f16* sH = smem;                       // [128][72] padded (+8 kills write conflicts)
  const int odd = lane & 1;
  const int j = (lane & 15) >> 1;
#pragma unroll
  for (int mf = 0; mf < 4; ++mf)
#pragma unroll
    for (int nfp = 0; nfp < 4; nfp += 2)
#pragma unroll
      for (int rg = 0; rg < 4; ++rg) {
        float v0 = acc[mf][nfp][rg];
        float v1 = acc[mf][nfp + 1][rg];
        float t0 = __shfl_xor(v0, 1);   // even lane: c3 of (nfp,   j)
        float t1 = __shfl_xor(v1, 1);   // odd  lane: c1 of (nfp+1, j)
        float c1 = odd ? t1 : v0;
        float c3 = odd ? v1 : t0;
        float ex = __expf(-c1);
        float hv = c1 * c3 * __builtin_amdgcn_rcpf(1.f + ex);
        int ml = wm + mf * 16 + (lane >> 4) * 4 + rg;
        int fl = (wn >> 1) + (nfp + odd) * 8 + j;
        sH[ml * 72 + fl] = (f16)(hv * s_w[ml]);
      }
  __syncthreads();
#pragma unroll
  for (int q = 0; q < 4; ++q) {
    int gi = q * 256 + t;
    int r = gi >> 3, gc = gi & 7;
    *(f16x8*)(hbuf + (long)(r0 + r) * FS + f0 + gc * 8) = *(const f16x8*)(sH + r * 72 + gc * 8);
  }
}

// ---------------- GEMM2: y[slot] = (h @ w2^T) slice (h pre-weighted) -------
// Grid: (D/128, MT) — x = d-slice (fastest) so consecutive blocks share the
// hbuf A-tile (fetched once, L2-hit for all 8 d-slices).
// ybuf != nullptr: plain fp16 vector stores into routed ybuf[RMAX][D].
// ybuf == nullptr: legacy fp32 atomicAdd scatter into out (sliced fallback).
__global__ __launch_bounds__(256) void ffn2_kernel(const f16* __restrict__ hbuf,
                                                   const f16* __restrict__ w2s,
                                                   const int* __restrict__ routed_token,
                                                   const int* __restrict__ meta,
                                                   float* __restrict__ out,
                                                   f16* __restrict__ ybuf,
                                                   int D, int FS) {
  const int e = meta[M_TE + blockIdx.y];
  if (e < 0) return;
  const int r0 = meta[M_TR + blockIdx.y];
  const int d0 = blockIdx.x * 128;

  // 128*136 f16 = 34 KiB (>= 2*128*64 staging). Stride 136 hw = 272 B:
  // 16B-aligned for f16x8 reads, 4-row write groups land on distinct-ish banks.
  __shared__ __align__(16) f16 smem[128 * 136];
  __shared__ int s_tok[128];
  f16* sA = smem;
  f16* sB = smem + 128 * 64;

  const int t = threadIdx.x;
  const int lane = t & 63;
  const int wave = t >> 6;
  const int wm = (wave & 1) * 64;
  const int wn = (wave >> 1) * 64;

  if (!ybuf && t < 128) s_tok[t] = routed_token[r0 + t];

  const int rb = t >> 3;
  const int sgg = (t & 7) ^ (rb & 7);
  const f16* aptr[4];
  const f16* bptr[4];
#pragma unroll
  for (int q = 0; q < 4; ++q) {
    int r = q * 32 + rb;
    aptr[q] = hbuf + (long)(r0 + r) * FS + sgg * 8;
    bptr[q] = w2s + ((long)e * D + d0 + r) * FS + sgg * 8;
  }
  f16* ldsA[4]; f16* ldsB[4];
#pragma unroll
  for (int q = 0; q < 4; ++q) {
    int gbase = (q * 256 + (t & ~63)) * 8;
    ldsA[q] = sA + gbase;
    ldsB[q] = sB + gbase;
  }

  fx4 acc[4][4];
#pragma unroll
  for (int i = 0; i < 4; ++i)
#pragma unroll
    for (int j = 0; j < 4; ++j) acc[i][j] = (fx4){0.f, 0.f, 0.f, 0.f};

  for (int kc = 0; kc < FS; kc += 64) {
#pragma unroll
    for (int q = 0; q < 4; ++q) {
      gload_lds16(aptr[q] + kc, ldsA[q]);
      gload_lds16(bptr[q] + kc, ldsB[q]);
    }
    __syncthreads();
#pragma unroll
    for (int ks = 0; ks < 2; ++ks) {
      f16x8 aF[4], bF[4];
      const int kg = ks * 4 + (lane >> 4);
#pragma unroll
      for (int mf = 0; mf < 4; ++mf) {
        int row = wm + mf * 16 + (lane & 15);
        aF[mf] = *(const f16x8*)(sA + row * 64 + (kg ^ (row & 7)) * 8);
      }
#pragma unroll
      for (int nf = 0; nf < 4; ++nf) {
        int row = wn + nf * 16 + (lane & 15);
        bF[nf] = *(const f16x8*)(sB + row * 64 + (kg ^ (row & 7)) * 8);
      }
#pragma unroll
      for (int mf = 0; mf < 4; ++mf)
#pragma unroll
        for (int nf = 0; nf < 4; ++nf)
          acc[mf][nf] = __builtin_amdgcn_mfma_f32_16x16x32_f16(aF[mf], bF[nf], acc[mf][nf], 0, 0, 0);
    }
    __syncthreads();
  }

  if (ybuf) {
    // transpose through LDS -> coalesced f16x8 row stores (no atomics)
    f16* sH = smem;                     // [128][136]
#pragma unroll
    for (int mf = 0; mf < 4; ++mf)
#pragma unroll
      for (int nf = 0; nf < 4; ++nf)
#pragma unroll
        for (int rg = 0; rg < 4; ++rg) {
          int row = wm + mf * 16 + (lane >> 4) * 4 + rg;
          int col = wn + nf * 16 + (lane & 15);
          sH[row * 136 + col] = (f16)acc[mf][nf][rg];
        }
    __syncthreads();
#pragma unroll
    for (int q = 0; q < 8; ++q) {
      int gi = q * 256 + t;
      int r = gi >> 4, c = (gi & 15) * 8;
      *(f16x8*)(ybuf + (long)(r0 + r) * D + d0 + c) = *(const f16x8*)(sH + r * 136 + c);
    }
  } else {
    // legacy: out[tok, d0+nl] += acc  (h pre-weighted; pads add 0.0)
#pragma unroll
    for (int mf = 0; mf < 4; ++mf) {
#pragma unroll
      for (int rg = 0; rg < 4; ++rg) {
        int row = wm + mf * 16 + (lane >> 4) * 4 + rg;
        long obase = (long)s_tok[row] * D + d0;
#pragma unroll
        for (int nf = 0; nf < 4; ++nf) {
          int nl = wn + nf * 16 + (lane & 15);
          atomicAdd(out + obase + nl, acc[mf][nf][rg]);
        }
      }
    }
  }
}

// ---------------- combine: out[tok] = y[slot0] + y[slot1] ------------------
// One block per token, D/8 threads, one f16x8 granule each. Memory-bound.
__global__ __launch_bounds__(256) void combine_kernel(const f16* __restrict__ y,
                                                      const int* __restrict__ slot_pos,
                                                      float* __restrict__ out, int D) {
  const long tok = blockIdx.x;
  const int g = threadIdx.x * 8;
  const int p0 = slot_pos[2 * tok];
  const int p1 = slot_pos[2 * tok + 1];
  f16x8 a = *(const f16x8*)(y + (long)p0 * D + g);
  f16x8 b = *(const f16x8*)(y + (long)p1 * D + g);
  float* op = out + tok * D + g;
  float4 o0 = {(float)a[0] + (float)b[0], (float)a[1] + (float)b[1],
               (float)a[2] + (float)b[2], (float)a[3] + (float)b[3]};
  float4 o1 = {(float)a[4] + (float)b[4], (float)a[5] + (float)b[5],
               (float)a[6] + (float)b[6], (float)a[7] + (float)b[7]};
  *(float4*)op = o0;
  *(float4*)(op + 4) = o1;
}

// ---------------------------------------------------------------------------
extern "C" void kernel_launch(void* const* d_in, const int* in_sizes, int n_in,
                              void* d_out, int out_size, void* d_ws, size_t ws_size,
                              hipStream_t stream) {
  const float* x  = (const float*)d_in[0];
  const float* gw = (const float*)d_in[1];
  const float* w1 = (const float*)d_in[2];
  const float* w2 = (const float*)d_in[3];
  const float* w3 = (const float*)d_in[4];
  float* out = (float*)d_out;

  const int E = NEXP;
  const int D = in_sizes[1] / E;                              // 1024
  const long N = (long)in_sizes[0] / D;                       // 16384
  const int F = (int)((long)in_sizes[2] / ((long)E * D));     // 2048
  const int MT = (int)(2 * N / 128 + E);                      // 264 m-tiles max
  const long RMAX = (long)MT * 128;
  const long out_bytes = (long)out_size * 4;
  const int n2 = (int)(2 * N);
  const int CB = (n2 + CHUNK - 1) / CHUNK;                    // 32 routing blocks

  char* base = (char*)d_ws;
  long off = 0;
  int*   meta         = (int*)(base + off); off += 8 * 1024;
  int*   topk_id      = (int*)(base + off); off += 2 * N * 4;
  float* topk_w       = (float*)(base + off); off += 2 * N * 4;
  int*   slot_pos     = (int*)(base + off); off += 2 * N * 4;
  int*   routed_token = (int*)(base + off); off += RMAX * 4;
  float* routed_w     = (float*)(base + off); off += RMAX * 4;
  off = (off + 255) & ~255L;
  const long small_end = off;

  const long w13_b = (long)E * 2 * F * D * 2;
  const long xb_b  = N * (long)D * 2;

  int S = 0; bool w13_in_dout = false; bool use_y = false;
  f16 *xb = nullptr, *w2s = nullptr, *hbuf = nullptr, *ybuf = nullptr, *w13 = nullptr;
  int FS = F;

  if (out_bytes >= w13_b) {
    const long w2s_b  = (long)E * D * F * 2;
    const long hbuf_b = RMAX * (long)F * 2;
    const long ybuf_b = RMAX * (long)D * 2;
    const long ovl_b  = (xb_b > ybuf_b) ? xb_b : ybuf_b;
    // Layout A: [small | w2s | hbuf | xb==ybuf overlay]  (xb dead after ffn1)
    if (small_end + w2s_b + hbuf_b + ovl_b <= (long)ws_size) {
      S = 1; w13_in_dout = true; use_y = true;
      long o = small_end;
      w2s  = (f16*)(base + o); o += w2s_b;
      hbuf = (f16*)(base + o); o += hbuf_b;
      xb   = (f16*)(base + o);
      ybuf = xb;                       // alias: ffn2 writes after ffn1's last xb read
      w13  = (f16*)d_out;
    } else if (small_end + xb_b + w2s_b + hbuf_b <= (long)ws_size) {
      // Layout B: previous fast path, atomic epilogue
      S = 1; w13_in_dout = true;
      long o = small_end;
      xb   = (f16*)(base + o); o += xb_b;
      w2s  = (f16*)(base + o); o += w2s_b;
      hbuf = (f16*)(base + o);
      w13  = (f16*)d_out;
    }
  }
  if (!S) {
    // sliced fallback: [small | xb | w2s(FS) | hbuf(FS) | w13(FS)]
    const int cands[4] = {2, 4, 8, 16};
    for (int ci = 0; ci < 4 && !S; ++ci) {
      int s = cands[ci];
      if (F % (64 * s)) continue;
      long FSl = F / s;
      long w2s_b  = (long)E * D * FSl * 2;
      long hbuf_b = RMAX * FSl * 2;
      long w13s_b = (long)E * 2 * FSl * D * 2;
      if (small_end + xb_b + w2s_b + hbuf_b + w13s_b <= (long)ws_size) {
        S = s; FS = (int)FSl;
        long o = small_end;
        xb   = (f16*)(base + o); o += xb_b;
        w2s  = (f16*)(base + o); o += w2s_b;
        hbuf = (f16*)(base + o); o += hbuf_b;
        w13  = (f16*)(base + o);
      }
    }
  }
  if (!S) return;

  hipMemsetAsync(meta, 0, 8 * 1024, stream);
  gate_kernel<<<(int)(N / 4), 256, 0, stream>>>(x, gw, xb, topk_id, topk_w, D);
  count_kernel<<<CB, 256, 0, stream>>>(topk_id, meta, n2);
  setup_kernel<<<1, 256, 0, stream>>>(meta, routed_token, routed_w, MT, CB);
  scatter_kernel<<<CB, 256, 0, stream>>>(topk_id, topk_w, meta, routed_token, routed_w,
                                         slot_pos, n2);

  const long n13 = (long)E * 2 * FS * (D / 4);
  const long nw2 = (long)E * D * (FS / 4);
  const int b13 = (int)((n13 + 255) / 256);
  const int bw2 = (int)((nw2 + 255) / 256);

  if (w13_in_dout) {
    cvt_w13_kernel<<<b13, 256, 0, stream>>>(w1, w3, w13, D, F, FS, 0);
    cvt_w2_kernel<<<bw2, 256, 0, stream>>>(w2, w2s, D, F, FS, 0);
    dim3 g1(FS / 64, MT);
    ffn1_kernel<<<g1, 256, 0, stream>>>(xb, w13, routed_token, routed_w, meta, hbuf, D, FS);
    dim3 g2(D / 128, MT);
    if (use_y) {
      // no out memset needed: combine fully overwrites out (w13 in d_out dead now)
      ffn2_kernel<<<g2, 256, 0, stream>>>(hbuf, w2s, routed_token, meta, out, ybuf, D, FS);
      combine_kernel<<<(int)N, D / 8, 0, stream>>>(ybuf, slot_pos, out, D);
    } else {
      hipMemsetAsync(out, 0, out_bytes, stream);   // w13 (in d_out) dead now
      ffn2_kernel<<<g2, 256, 0, stream>>>(hbuf, w2s, routed_token, meta, out, nullptr, D, FS);
    }
  } else {
    hipMemsetAsync(out, 0, out_bytes, stream);
    for (int s = 0; s < S; ++s) {
      int fbase = s * FS;
      cvt_w13_kernel<<<b13, 256, 0, stream>>>(w1, w3, w13, D, F, FS, fbase);
      cvt_w2_kernel<<<bw2, 256, 0, stream>>>(w2, w2s, D, F, FS, fbase);
      dim3 g1(FS / 64, MT);
      ffn1_kernel<<<g1, 256, 0, stream>>>(xb, w13, routed_token, routed_w, meta, hbuf, D, FS);
      dim3 g2(D / 128, MT);
      ffn2_kernel<<<g2, 256, 0, stream>>>(hbuf, w2s, routed_token, meta, out, nullptr, D, FS);
    }
  }
}